// Round 4
// baseline (91.345 us; speedup 1.0000x reference)
//
#include <hip/hip_runtime.h>

#define LPOS 256
#define CCH 20
#define BB 4096
#define LC 5120   // LPOS*CCH
#define LC4 1280  // LC/4

// ---------------- Kernel 1: seq extraction + linear term -------------------
__global__ __launch_bounds__(256) void k_prepare(
    const float* __restrict__ x_lc, const float* __restrict__ theta_0,
    const float* __restrict__ theta_lc, unsigned char* __restrict__ seqB,
    float* __restrict__ out)
{
    const int b = blockIdx.x;
    const int l = threadIdx.x;
    const float* xp = x_lc + (size_t)b * LC + (size_t)l * CCH;
    const float4* xp4 = reinterpret_cast<const float4*>(xp);
    float v[CCH];
#pragma unroll
    for (int q = 0; q < 5; ++q) {
        float4 t = xp4[q];
        v[q * 4 + 0] = t.x; v[q * 4 + 1] = t.y;
        v[q * 4 + 2] = t.z; v[q * 4 + 3] = t.w;
    }
    int s = 0; float best = v[0];
#pragma unroll
    for (int c = 1; c < CCH; ++c) { if (v[c] > best) { best = v[c]; s = c; } }

    seqB[(size_t)b * LPOS + l] = (unsigned char)s;

    float lin = theta_lc[l * CCH + s];
#pragma unroll
    for (int off = 32; off > 0; off >>= 1) lin += __shfl_down(lin, off, 64);
    __shared__ float partial[4];
    const int wave = threadIdx.x >> 6;
    const int lane = threadIdx.x & 63;
    if (lane == 0) partial[wave] = lin;
    __syncthreads();
    if (threadIdx.x == 0)
        out[b] = theta_0[0] + partial[0] + partial[1] + partial[2] + partial[3];
}

// ---------------- Kernel 2: masked pairwise quadratic form -----------------
// One-hot x + strict l2 > l1 => quad[b] = sum over pairs of table lookups.
// Block (tile, g): batches [tile*512,+512), rows l1 in {g, 254-g}.
// l2 in absolute 16-aligned chunks m; per chunk the 20x320 subtable
// [c1][j*20+c2] is staged as bf16 into a DOUBLE-BUFFERED LDS table:
//   iter t: issue global loads for chunk t+1 -> gather chunk t from buf[t&1]
//           -> cvt+ds_write chunk t+1 into buf[t&1 ^ 1] -> one barrier.
#define QTHREADS 512
#define TILEB 512
#define NTILES (BB / TILEB)    // 8
#define NGROUPS 128
#define ROW 324                // bf16 elems/row: 320 payload + 4 pad (bank spread)
#define BUFELEMS (CCH * ROW)   // 6480 shorts = 12960 B per buffer

__device__ __forceinline__ unsigned short f2bf(float f) {
    unsigned u = __float_as_uint(f);
    u += 0x7FFFu + ((u >> 16) & 1u);     // RNE (inputs are finite normals)
    return (unsigned short)(u >> 16);
}
__device__ __forceinline__ float bf2f(unsigned short h) {
    return __uint_as_float(((unsigned)h) << 16);
}

__global__ __launch_bounds__(QTHREADS) void k_quad(
    const float* __restrict__ Theta,          // (5120, 5120) f32 row-major
    const unsigned char* __restrict__ seqB,   // (B, L)
    float* __restrict__ out)
{
    __shared__ unsigned short Tl[2 * BUFELEMS];   // 25920 B

    const int tile = blockIdx.x;
    const int g    = blockIdx.y;
    const int tid  = threadIdx.x;
    const int b    = tile * TILEB + tid;

    const unsigned char* sb = seqB + (size_t)b * LPOS;
    const uint4* sb4 = reinterpret_cast<const uint4*>(sb);

    const int l1a = g, l1b = 254 - g;
    const int m0a = (l1a + 1) >> 4, jloa = (l1a + 1) & 15;
    const int m0b = (l1b + 1) >> 4, jlob = (l1b + 1) & 15;
    const int n1 = 16 - m0a;
    const int NT = (g == 127) ? n1 : n1 + (16 - m0b);

    const int basea = (int)sb[l1a] * ROW;
    const int baseb = (int)sb[l1b] * ROW;

    // staging decomposition: 1600 float4 units = 3 sweeps of 512 + tail 64
    const int r0 = tid / 80,          o0 = tid - r0 * 80;
    const int u1 = tid + 512;  const int r1 = u1 / 80, o1 = u1 - r1 * 80;
    const int u2 = tid + 1024; const int r2 = u2 / 80, o2 = u2 - r2 * 80;
    const int e0 = r0 * ROW + o0 * 4;
    const int e1 = r1 * ROW + o1 * 4;
    const int e2 = r2 * ROW + o2 * 4;
    const int e3 = 19 * ROW + (16 + tid) * 4;          // tail (tid<64)
    const int g0 = r0 * LC4 + o0;
    const int g1 = r1 * LC4 + o1;
    const int g2 = r2 * LC4 + o2;
    const int g3 = 19 * LC4 + 16 + tid;

    const float4* Th4 = reinterpret_cast<const float4*>(Theta);

    float4 sA, sB, sC, sD;
    float acc = 0.f;

    // chunk t -> (l1, m, base, jlo); all wave-uniform except base
    auto chunkof = [&](int t, int& l1, int& m, int& base, int& jlo) {
        if (t < n1) { l1 = l1a; m = m0a + t; base = basea; jlo = (t == 0) ? jloa : 0; }
        else { l1 = l1b; m = m0b + (t - n1); base = baseb; jlo = (t == n1) ? jlob : 0; }
    };
    auto ldchunk = [&](int l1n, int mn) {
        const float4* Tr = Th4 + (size_t)l1n * CCH * LC4 + (size_t)mn * 80;
        sA = Tr[g0]; sB = Tr[g1]; sC = Tr[g2];
        if (tid < 64) sD = Tr[g3];
    };
    auto wrchunk = [&](int dst) {
        unsigned short* D = Tl + dst * BUFELEMS;
        *reinterpret_cast<ushort4*>(D + e0) =
            make_ushort4(f2bf(sA.x), f2bf(sA.y), f2bf(sA.z), f2bf(sA.w));
        *reinterpret_cast<ushort4*>(D + e1) =
            make_ushort4(f2bf(sB.x), f2bf(sB.y), f2bf(sB.z), f2bf(sB.w));
        *reinterpret_cast<ushort4*>(D + e2) =
            make_ushort4(f2bf(sC.x), f2bf(sC.y), f2bf(sC.z), f2bf(sC.w));
        if (tid < 64)
            *reinterpret_cast<ushort4*>(D + e3) =
                make_ushort4(f2bf(sD.x), f2bf(sD.y), f2bf(sD.z), f2bf(sD.w));
    };

    // prologue: stage chunk 0 into buf 0, prefetch its seq word
    {
        int l1, m, base, jlo; chunkof(0, l1, m, base, jlo);
        ldchunk(l1, m);
        wrchunk(0);
    }
    uint4 sq;
    {
        int l1, m, base, jlo; chunkof(0, l1, m, base, jlo);
        sq = sb4[m];
    }
    __syncthreads();

    for (int t = 0; t < NT; ++t) {
        const int cur = t & 1;
        int l1, m, base, jlo; chunkof(t, l1, m, base, jlo);
        const bool more = (t + 1 < NT);
        if (more) {
            int l1n, mn, basen, jlon; chunkof(t + 1, l1n, mn, basen, jlon);
            ldchunk(l1n, mn);            // issue early: hides under gathers
            const unsigned w0 = sq.x, w1 = sq.y, w2 = sq.z, w3 = sq.w;
            sq = sb4[mn];                // prefetch next chunk's seq word
            const unsigned short* T = Tl + cur * BUFELEMS + base;
            if (jlo) {
#pragma unroll
                for (int j = 0; j < 16; ++j) {
                    unsigned w = (j < 4) ? w0 : (j < 8) ? w1 : (j < 12) ? w2 : w3;
                    int s2 = (w >> ((j & 3) * 8)) & 0xFF;
                    float v = bf2f(T[j * CCH + s2]);
                    acc += (j >= jlo) ? v : 0.f;
                }
            } else {
#pragma unroll
                for (int j = 0; j < 16; ++j) {
                    unsigned w = (j < 4) ? w0 : (j < 8) ? w1 : (j < 12) ? w2 : w3;
                    int s2 = (w >> ((j & 3) * 8)) & 0xFF;
                    acc += bf2f(T[j * CCH + s2]);
                }
            }
            wrchunk(cur ^ 1);            // write late (after vmcnt wait)
        } else {
            const unsigned w0 = sq.x, w1 = sq.y, w2 = sq.z, w3 = sq.w;
            const unsigned short* T = Tl + cur * BUFELEMS + base;
            if (jlo) {
#pragma unroll
                for (int j = 0; j < 16; ++j) {
                    unsigned w = (j < 4) ? w0 : (j < 8) ? w1 : (j < 12) ? w2 : w3;
                    int s2 = (w >> ((j & 3) * 8)) & 0xFF;
                    float v = bf2f(T[j * CCH + s2]);
                    acc += (j >= jlo) ? v : 0.f;
                }
            } else {
#pragma unroll
                for (int j = 0; j < 16; ++j) {
                    unsigned w = (j < 4) ? w0 : (j < 8) ? w1 : (j < 12) ? w2 : w3;
                    int s2 = (w >> ((j & 3) * 8)) & 0xFF;
                    acc += bf2f(T[j * CCH + s2]);
                }
            }
        }
        __syncthreads();
    }
    atomicAdd(&out[b], acc);
}

extern "C" void kernel_launch(void* const* d_in, const int* in_sizes, int n_in,
                              void* d_out, int out_size, void* d_ws, size_t ws_size,
                              hipStream_t stream) {
    const float* x_lc       = (const float*)d_in[0];
    const float* theta_0    = (const float*)d_in[1];
    const float* theta_lc   = (const float*)d_in[2];
    const float* theta_lclc = (const float*)d_in[3];
    // d_in[4] = mask (bool) — implicit: we only iterate l2 > l1.
    float* out = (float*)d_out;
    unsigned char* seqB = (unsigned char*)d_ws;   // B*L = 1 MB

    k_prepare<<<dim3(BB), dim3(256), 0, stream>>>(x_lc, theta_0, theta_lc, seqB, out);
    k_quad<<<dim3(NTILES, NGROUPS), dim3(QTHREADS), 0, stream>>>(theta_lclc, seqB, out);
}

// Round 5
// 80.342 us; speedup vs baseline: 1.1369x; 1.1369x over previous
//
#include <hip/hip_runtime.h>

#define LPOS 256
#define CCH 20
#define BB 4096
#define LC 5120   // LPOS*CCH

// ---------------- Kernel 1: seq extraction + linear term -------------------
__global__ __launch_bounds__(256) void k_prepare(
    const float* __restrict__ x_lc, const float* __restrict__ theta_0,
    const float* __restrict__ theta_lc, unsigned char* __restrict__ seqB,
    float* __restrict__ out)
{
    const int b = blockIdx.x;
    const int l = threadIdx.x;
    const float* xp = x_lc + (size_t)b * LC + (size_t)l * CCH;
    const float4* xp4 = reinterpret_cast<const float4*>(xp);
    float v[CCH];
#pragma unroll
    for (int q = 0; q < 5; ++q) {
        float4 t = xp4[q];
        v[q * 4 + 0] = t.x; v[q * 4 + 1] = t.y;
        v[q * 4 + 2] = t.z; v[q * 4 + 3] = t.w;
    }
    int s = 0; float best = v[0];
#pragma unroll
    for (int c = 1; c < CCH; ++c) { if (v[c] > best) { best = v[c]; s = c; } }

    seqB[(size_t)b * LPOS + l] = (unsigned char)s;

    float lin = theta_lc[l * CCH + s];
#pragma unroll
    for (int off = 32; off > 0; off >>= 1) lin += __shfl_down(lin, off, 64);
    __shared__ float partial[4];
    const int wave = threadIdx.x >> 6;
    const int lane = threadIdx.x & 63;
    if (lane == 0) partial[wave] = lin;
    __syncthreads();
    if (threadIdx.x == 0)
        out[b] = theta_0[0] + partial[0] + partial[1] + partial[2] + partial[3];
}

// ---------------- Kernel 2: masked pairwise quadratic form -----------------
// quad[b] = sum_{l1<l2} Theta[l1,s1,l2,s2] (one-hot x => pure table lookups).
// Block (tile, g): batches [tile*1024,+1024), rows l1 in {g, 254-g}.
// l2 in absolute 16-aligned chunks m; chunk table is LDS [j][s1][s2] (6400
// f32, UNPADDED j-major: bank=(j*16+s1*20+s2)%32 ~uniform), double-buffered,
// staged with global_load_lds (25 x 1KB wave-segments, no VGPR round-trip).
// One barrier per chunk; next chunk's loads are in flight during gathers.
#define QTHREADS 1024
#define TILEB 1024
#define NTILES (BB / TILEB)   // 4
#define NGROUPS 128
#define TBL 6400              // 16*20*20 f32 per chunk table
#define SEGS 25               // 1 KB gload_lds segments per table

__global__ __launch_bounds__(QTHREADS) void k_quad(
    const float* __restrict__ Theta,          // (5120, 5120) f32 row-major
    const unsigned char* __restrict__ seqB,   // (B, L)
    float* __restrict__ out)
{
    __shared__ float Tl[2 * TBL];   // 51200 B

    const int tile = blockIdx.x;
    const int g    = blockIdx.y;
    const int tid  = threadIdx.x;
    const int b    = tile * TILEB + tid;
    const int wave = tid >> 6;
    const int lane = tid & 63;

    const unsigned char* sb = seqB + (size_t)b * LPOS;
    const uint4* sb4 = reinterpret_cast<const uint4*>(sb);

    const int l1a = g, l1b = 254 - g;
    const int m0a = (l1a + 1) >> 4, jloa = (l1a + 1) & 15;
    const int m0b = (l1b + 1) >> 4, jlob = (l1b + 1) & 15;
    const int n1 = 16 - m0a;
    const int NT = (g == 127) ? n1 : n1 + (16 - m0b);

    const int basea = (int)sb[l1a] * CCH;   // s1*20
    const int baseb = (int)sb[l1b] * CCH;

    // chunk t -> (l1, m, gather base, jlo); all wave-uniform except base
    auto chunk_params = [&](int t, int& l1, int& m, int& base, int& jlo) {
        if (t < n1) { l1 = l1a; m = m0a + t; base = basea; jlo = (t == 0) ? jloa : 0; }
        else { l1 = l1b; m = m0b + (t - n1); base = baseb; jlo = (t == n1) ? jlob : 0; }
    };

    // Stage chunk (l1, m) into buffer dst: 25 segments x 64 lanes x 16 B.
    // f32-unit u = seg*64+lane covers table elems 4u..4u+3: row r = u/5
    // (r = j*20+s1), col c = u%5 -> global row (l1*20+s1), cols
    // (m*16+j)*20 + 4c..+3 (16B-contiguous; rows start at 80B multiples).
    auto stage = [&](int l1, int m, int dst) {
#pragma unroll
        for (int k = 0; k < 2; ++k) {
            const int seg = wave + k * 16;
            if (seg < SEGS) {
                const int u = seg * 64 + lane;
                const int r = u / 5, c = u - r * 5;
                const int j = r / 20, s1 = r - j * 20;
                const float* gp = Theta + (size_t)(l1 * CCH + s1) * LC
                                        + (m * 16 + j) * CCH + c * 4;
                float* lp = Tl + dst * TBL + seg * 256;   // wave-uniform dest
                __builtin_amdgcn_global_load_lds(
                    (const __attribute__((address_space(1))) void*)gp,
                    (__attribute__((address_space(3))) void*)lp, 16, 0, 0);
            }
        }
    };

    // prologue: stage chunk 0 -> buf 0; prefetch its seq word
    uint4 sq;
    {
        int l1, m, base, jlo; chunk_params(0, l1, m, base, jlo);
        stage(l1, m, 0);
        sq = sb4[m];
    }
    __syncthreads();   // drains vmcnt -> buf 0 ready

    float acc = 0.f;
    for (int t = 0; t < NT; ++t) {
        const int cur = t & 1;
        int l1, m, base, jlo; chunk_params(t, l1, m, base, jlo);
        const unsigned w0 = sq.x, w1 = sq.y, w2 = sq.z, w3 = sq.w;  // current
        if (t + 1 < NT) {                  // issue next chunk's async loads
            int l1n, mn, bn, jn; chunk_params(t + 1, l1n, mn, bn, jn);
            stage(l1n, mn, cur ^ 1);
            sq = sb4[mn];                  // prefetch next seq word
        }
        const float* T = Tl + cur * TBL + base;
        if (jlo) {                          // ragged first chunk of a row
#pragma unroll
            for (int j = 0; j < 16; ++j) {
                const unsigned w = (j < 4) ? w0 : (j < 8) ? w1 : (j < 12) ? w2 : w3;
                const int s2 = (w >> ((j & 3) * 8)) & 0xFF;
                float v = T[j * 400 + s2];
                acc += (j >= jlo) ? v : 0.f;
            }
        } else {
#pragma unroll
            for (int j = 0; j < 16; ++j) {
                const unsigned w = (j < 4) ? w0 : (j < 8) ? w1 : (j < 12) ? w2 : w3;
                const int s2 = (w >> ((j & 3) * 8)) & 0xFF;
                acc += T[j * 400 + s2];
            }
        }
        __syncthreads();   // gathers done + next buffer's loads drained
    }
    atomicAdd(&out[b], acc);
}

extern "C" void kernel_launch(void* const* d_in, const int* in_sizes, int n_in,
                              void* d_out, int out_size, void* d_ws, size_t ws_size,
                              hipStream_t stream) {
    const float* x_lc       = (const float*)d_in[0];
    const float* theta_0    = (const float*)d_in[1];
    const float* theta_lc   = (const float*)d_in[2];
    const float* theta_lclc = (const float*)d_in[3];
    // d_in[4] = mask (bool) — implicit: we only iterate l2 > l1.
    float* out = (float*)d_out;
    unsigned char* seqB = (unsigned char*)d_ws;   // B*L = 1 MB

    k_prepare<<<dim3(BB), dim3(256), 0, stream>>>(x_lc, theta_0, theta_lc, seqB, out);
    k_quad<<<dim3(NTILES, NGROUPS), dim3(QTHREADS), 0, stream>>>(theta_lclc, seqB, out);
}